// Round 3
// baseline (1258.854 us; speedup 1.0000x reference)
//
#include <hip/hip_runtime.h>
#include <stdint.h>

#define L_LAYERS 16
#define QD 2048
#define BATCH 4096

typedef __attribute__((ext_vector_type(8))) __bf16 bf16x8;
typedef __attribute__((ext_vector_type(4))) float f32x4;
typedef __attribute__((address_space(3))) uint32_t lds32_t;
typedef const __attribute__((address_space(1))) uint32_t glob32_t;

// async global->LDS, 16B per lane. LDS dest is wave-uniform base + lane*16.
__device__ __forceinline__ void async_load16(const void* g, void* l) {
    __builtin_amdgcn_global_load_lds((glob32_t*)(uintptr_t)g, (lds32_t*)(uintptr_t)l,
                                     16, 0, 0);
}

// float -> bf16 bits, round-to-nearest-even.
__device__ __forceinline__ unsigned short f2bf(float f) {
    uint32_t u = __float_as_uint(f);
    u += 0x7FFFu + ((u >> 16) & 1u);
    return (unsigned short)(u >> 16);
}

// ---------------------------------------------------------------------------
// scales[l][k] = cos(a0/2)*cos(a1/2)*cos(a2/2)
__global__ void scales_kernel(const float* __restrict__ ang, float* __restrict__ sc, int n) {
    int i = blockIdx.x * 256 + threadIdx.x;
    if (i < n) {
        float a0 = ang[3 * i + 0], a1 = ang[3 * i + 1], a2 = ang[3 * i + 2];
        sc[i] = __cosf(a0 * 0.5f) * __cosf(a1 * 0.5f) * __cosf(a2 * 0.5f);
    }
}

// fp32 input state -> bf16
__global__ void convert_in_kernel(const float* __restrict__ in,
                                  unsigned short* __restrict__ out, int n4) {
    int i = blockIdx.x * 256 + threadIdx.x;
    if (i < n4) {
        float4 v = ((const float4*)in)[i];
        ushort4 o;
        o.x = f2bf(v.x); o.y = f2bf(v.y); o.z = f2bf(v.z); o.w = f2bf(v.w);
        ((ushort4*)out)[i] = o;
    }
}

// 64x64 tile: dst[n][k] = bf16( src[k][n] * scale[k] )   (transpose + scale-fold)
__device__ __forceinline__ void conv_tile_body(const float* __restrict__ src,
                                               const float* __restrict__ srow,
                                               unsigned short* __restrict__ dst) {
    __shared__ __align__(16) unsigned short tile[64][72];  // pad keeps 16B-aligned rows
    const int t = threadIdx.x;
    const int k0 = blockIdx.y * 64, n0 = blockIdx.x * 64;
    const int r = t >> 4;           // 0..15
    const int c = (t & 15) * 4;     // 0..60
#pragma unroll
    for (int rr = 0; rr < 64; rr += 16) {
        int k = k0 + r + rr;
        float s = srow ? srow[k] : 1.0f;
        float4 v = *(const float4*)(src + (size_t)k * QD + n0 + c);
        tile[c + 0][r + rr] = f2bf(v.x * s);
        tile[c + 1][r + rr] = f2bf(v.y * s);
        tile[c + 2][r + rr] = f2bf(v.z * s);
        tile[c + 3][r + rr] = f2bf(v.w * s);
    }
    __syncthreads();
    const int wr = t >> 3;          // 0..31
    const int wc = (t & 7) * 8;     // 0..56
#pragma unroll
    for (int rr = 0; rr < 64; rr += 32) {
        *(float4*)(dst + (size_t)(n0 + wr + rr) * QD + k0 + wc) =
            *(const float4*)(&tile[wr + rr][wc]);
    }
}

// all 17 matrices in one launch (z = layer; z==16 -> measurement basis, no scale)
__global__ void convert_w_all(const float* __restrict__ W, const float* __restrict__ Mb,
                              const float* __restrict__ sc, unsigned short* __restrict__ out) {
    const int z = blockIdx.z;
    const float* src = (z < L_LAYERS) ? (W + (size_t)z * QD * QD) : Mb;
    const float* srow = (z < L_LAYERS) ? (sc + z * QD) : nullptr;
    unsigned short* dst = out + (size_t)z * QD * QD;
    conv_tile_body(src, srow, dst);
}

// single-matrix variant (fallback when ws is small)
__global__ void convert_w_one(const float* __restrict__ src, const float* __restrict__ srow,
                              unsigned short* __restrict__ dst) {
    conv_tile_body(src, srow, dst);
}

// ---------------------------------------------------------------------------
// C[M=4096][N=2048] = A[M][K] * Bt[N][K]^T, bf16 in, fp32 accumulate.
// 64x128 (MxN) block tile -> grid 64x16 = 1024 blocks = 4 blocks/CU (16
// waves/CU) to hide the per-round barrier drain that starved the 512-block
// 128x128 version (2 blocks/CU, grid-capped). BK=64 as two BK=32 panels.
// 4 waves as 2(m) x 2(n); each wave 32x64 = 2x4 MFMA frags (acc = 32 VGPR).
// LDS = 8KB(A) + 16KB(B) = 24KB/block -> 4 blocks/CU fits 96KB/160KB.
template <int OUT_BF16>
__global__ __launch_bounds__(256, 4) void gemm_kernel(const unsigned short* __restrict__ A,
                                                      const unsigned short* __restrict__ Bt,
                                                      void* __restrict__ Cout) {
    __shared__ __align__(16) unsigned short ldsA[64 * 64];   // panel p at p*2048
    __shared__ __align__(16) unsigned short ldsB[128 * 64];  // panel p at p*4096
    const int t = threadIdx.x;
    const int n0 = blockIdx.x * 128;
    const int m0 = blockIdx.y * 64;
    const int lane = t & 63;
    const int wave = t >> 6;
    const int wm = (wave & 1) * 32;
    const int wn = (wave >> 1) * 64;
    const int fr = lane & 15;      // A: m in 16-tile; B: n in 16-tile; C: col
    const int quad = lane >> 4;    // k-group for frags; row-group for C

    f32x4 acc[2][4] = {};

    // staging: thread t covers row (t>>2) of a 64-row span, 8 k-elems at (t&3)*8
    const int sr = t >> 2;          // 0..63
    const int scol = (t & 3) * 8;   // 0,8,16,24
    const unsigned short* ga = A + (size_t)(m0 + sr) * QD + scol;
    const unsigned short* gb = Bt + (size_t)(n0 + sr) * QD + scol;
    unsigned short* la = ldsA + t * 8;   // +2048 shorts = next 4KB chunk
    unsigned short* lb = ldsB + t * 8;

    for (int k0 = 0; k0 < QD; k0 += 64) {
        __syncthreads();  // previous round's compute done before overwrite
        // A panels: [64][32] each; panel0 k 0..31, panel1 k 32..63
        async_load16(ga, la);
        async_load16(ga + 32, la + 2048);
        // B panels: [128][32] each (two 64-row halves per panel)
        async_load16(gb, lb);
        async_load16(gb + 64 * QD, lb + 2048);
        async_load16(gb + 32, lb + 4096);
        async_load16(gb + 32 + 64 * QD, lb + 6144);
        ga += 64;
        gb += 64;
        __syncthreads();  // staging complete (compiler inserts vmcnt(0))

#pragma unroll
        for (int kk = 0; kk < 2; kk++) {
            const unsigned short* pa = ldsA + kk * 2048;
            const unsigned short* pb = ldsB + kk * 4096;
            bf16x8 af[2], bfr[4];
#pragma unroll
            for (int i = 0; i < 2; i++)
                af[i] = *(const bf16x8*)(pa + (wm + i * 16 + fr) * 32 + quad * 8);
#pragma unroll
            for (int j = 0; j < 4; j++)
                bfr[j] = *(const bf16x8*)(pb + (wn + j * 16 + fr) * 32 + quad * 8);
#pragma unroll
            for (int i = 0; i < 2; i++)
#pragma unroll
                for (int j = 0; j < 4; j++)
                    acc[i][j] = __builtin_amdgcn_mfma_f32_16x16x32_bf16(af[i], bfr[j],
                                                                        acc[i][j], 0, 0, 0);
        }
    }

    // epilogue: C/D layout col=lane&15, row=quad*4+reg  (m89/m91-verified)
#pragma unroll
    for (int i = 0; i < 2; i++) {
        const int gr = m0 + wm + i * 16 + quad * 4;
#pragma unroll
        for (int j = 0; j < 4; j++) {
            const int gc = n0 + wn + j * 16 + fr;
#pragma unroll
            for (int r = 0; r < 4; r++) {
                float v = acc[i][j][r];
                if (OUT_BF16)
                    ((unsigned short*)Cout)[(size_t)(gr + r) * QD + gc] = f2bf(v);
                else
                    ((float*)Cout)[(size_t)(gr + r) * QD + gc] = v;
            }
        }
    }
}

// ---------------------------------------------------------------------------
extern "C" void kernel_launch(void* const* d_in, const int* in_sizes, int n_in,
                              void* d_out, int out_size, void* d_ws, size_t ws_size,
                              hipStream_t stream) {
    const float* input_state = (const float*)d_in[0];  // [4096][2048]
    const float* angles      = (const float*)d_in[1];  // [16][2048][3]
    const float* W           = (const float*)d_in[2];  // [16][2048][2048]
    const float* Mb          = (const float*)d_in[3];  // [2048][2048]

    char* ws = (char*)d_ws;
    float* scales = (float*)ws;                       // 16*2048*4 = 128KB
    size_t off = 131072;
    unsigned short* s0 = (unsigned short*)(ws + off); off += (size_t)BATCH * QD * 2;
    unsigned short* s1 = (unsigned short*)(ws + off); off += (size_t)BATCH * QD * 2;
    unsigned short* Wb = (unsigned short*)(ws + off);
    const size_t mat = (size_t)QD * QD;
    const bool full = ws_size >= off + 17 * mat * 2;  // ~176 MB total

    scales_kernel<<<(L_LAYERS * QD + 255) / 256, 256, 0, stream>>>(angles, scales,
                                                                   L_LAYERS * QD);
    convert_in_kernel<<<(BATCH * QD / 4 + 255) / 256, 256, 0, stream>>>(
        input_state, s0, BATCH * QD / 4);

    if (full) {
        dim3 g(QD / 64, QD / 64, L_LAYERS + 1);
        convert_w_all<<<g, 256, 0, stream>>>(W, Mb, scales, Wb);
    }

    dim3 gg(QD / 128, BATCH / 64);  // 16 x 64 = 1024 blocks
    unsigned short* cur = s0;
    unsigned short* nxt = s1;
    for (int l = 0; l < L_LAYERS; l++) {
        unsigned short* wb = full ? (Wb + (size_t)l * mat) : Wb;
        if (!full) {
            dim3 g(QD / 64, QD / 64, 1);
            convert_w_one<<<g, 256, 0, stream>>>(W + (size_t)l * mat, scales + l * QD, Wb);
        }
        gemm_kernel<1><<<gg, 256, 0, stream>>>(cur, wb, nxt);
        unsigned short* tmp = cur; cur = nxt; nxt = tmp;
    }
    unsigned short* mb = full ? (Wb + (size_t)L_LAYERS * mat) : Wb;
    if (!full) {
        dim3 g(QD / 64, QD / 64, 1);
        convert_w_one<<<g, 256, 0, stream>>>(Mb, nullptr, Wb);
    }
    gemm_kernel<0><<<gg, 256, 0, stream>>>(cur, mb, d_out);
}

// Round 4
// 796.559 us; speedup vs baseline: 1.5804x; 1.5804x over previous
//
#include <hip/hip_runtime.h>
#include <stdint.h>

#define L_LAYERS 16
#define QD 2048
#define BATCH 4096

typedef __attribute__((ext_vector_type(8))) __bf16 bf16x8;
typedef __attribute__((ext_vector_type(4))) float f32x4;
typedef __attribute__((address_space(3))) uint32_t lds32_t;
typedef const __attribute__((address_space(1))) uint32_t glob32_t;

// async global->LDS, 16B per lane. LDS dest is wave-uniform base + lane*16.
__device__ __forceinline__ void async_load16(const void* g, void* l) {
    __builtin_amdgcn_global_load_lds((glob32_t*)(uintptr_t)g, (lds32_t*)(uintptr_t)l,
                                     16, 0, 0);
}

// float -> bf16 bits, round-to-nearest-even.
__device__ __forceinline__ unsigned short f2bf(float f) {
    uint32_t u = __float_as_uint(f);
    u += 0x7FFFu + ((u >> 16) & 1u);
    return (unsigned short)(u >> 16);
}

// ---------------------------------------------------------------------------
// scales[l][k] = cos(a0/2)*cos(a1/2)*cos(a2/2)
__global__ void scales_kernel(const float* __restrict__ ang, float* __restrict__ sc, int n) {
    int i = blockIdx.x * 256 + threadIdx.x;
    if (i < n) {
        float a0 = ang[3 * i + 0], a1 = ang[3 * i + 1], a2 = ang[3 * i + 2];
        sc[i] = __cosf(a0 * 0.5f) * __cosf(a1 * 0.5f) * __cosf(a2 * 0.5f);
    }
}

// fp32 input state -> bf16
__global__ void convert_in_kernel(const float* __restrict__ in,
                                  unsigned short* __restrict__ out, int n4) {
    int i = blockIdx.x * 256 + threadIdx.x;
    if (i < n4) {
        float4 v = ((const float4*)in)[i];
        ushort4 o;
        o.x = f2bf(v.x); o.y = f2bf(v.y); o.z = f2bf(v.z); o.w = f2bf(v.w);
        ((ushort4*)out)[i] = o;
    }
}

// A-form: dst[m][k] = bf16( W[2z][m][k] * s[2z][m] )  (row scale, no transpose)
// One z per even-position weight (0-indexed layers 0,2,...,14).
__global__ void convert_a_all(const float* __restrict__ W, const float* __restrict__ sc,
                              unsigned short* __restrict__ out) {
    const int z = blockIdx.z;
    const float* src = W + (size_t)(2 * z) * QD * QD;
    const float* srow = sc + (2 * z) * QD;
    unsigned short* dst = out + (size_t)z * QD * QD;
    int i = blockIdx.x * 256 + threadIdx.x;      // float4 index; 512 per row
    float s = srow[i >> 9];
    float4 v = ((const float4*)src)[i];
    ushort4 o;
    o.x = f2bf(v.x * s); o.y = f2bf(v.y * s); o.z = f2bf(v.z * s); o.w = f2bf(v.w * s);
    ((ushort4*)dst)[i] = o;
}

// 64x64 tile: dst[n][k] = bf16( src[k][n] * scale[k] )   (transpose + scale-fold)
__device__ __forceinline__ void conv_tile_body(const float* __restrict__ src,
                                               const float* __restrict__ srow,
                                               unsigned short* __restrict__ dst) {
    __shared__ __align__(16) unsigned short tile[64][72];  // pad keeps 16B-aligned rows
    const int t = threadIdx.x;
    const int k0 = blockIdx.y * 64, n0 = blockIdx.x * 64;
    const int r = t >> 4;           // 0..15
    const int c = (t & 15) * 4;     // 0..60
#pragma unroll
    for (int rr = 0; rr < 64; rr += 16) {
        int k = k0 + r + rr;
        float s = srow ? srow[k] : 1.0f;
        float4 v = *(const float4*)(src + (size_t)k * QD + n0 + c);
        tile[c + 0][r + rr] = f2bf(v.x * s);
        tile[c + 1][r + rr] = f2bf(v.y * s);
        tile[c + 2][r + rr] = f2bf(v.z * s);
        tile[c + 3][r + rr] = f2bf(v.w * s);
    }
    __syncthreads();
    const int wr = t >> 3;          // 0..31
    const int wc = (t & 7) * 8;     // 0..56
#pragma unroll
    for (int rr = 0; rr < 64; rr += 32) {
        *(float4*)(dst + (size_t)(n0 + wr + rr) * QD + k0 + wc) =
            *(const float4*)(&tile[wr + rr][wc]);
    }
}

// Bt-form for odd-position weights (layers 1,3,...,15) at z=0..7; z=8 -> M^T.
__global__ void convert_b_all(const float* __restrict__ W, const float* __restrict__ Mb,
                              const float* __restrict__ sc, unsigned short* __restrict__ out) {
    const int z = blockIdx.z;
    const float* src = (z < 8) ? (W + (size_t)(2 * z + 1) * QD * QD) : Mb;
    const float* srow = (z < 8) ? (sc + (2 * z + 1) * QD) : nullptr;
    unsigned short* dst = out + (size_t)z * QD * QD;
    conv_tile_body(src, srow, dst);
}

// ---------------------------------------------------------------------------
// C[M][N=2048] = A[M][K=2048] * Bt[N][K]^T, bf16 in, fp32 accumulate.
// TM x 128 block tile, BK=64 as two BK=32 panels ([TM][32] / [128][32]) so
// global_load_lds stays lane-contiguous and LDS frag reads keep the m97 bank
// profile. 4 waves as 2(m) x 2(n); each wave (TM/32) x 4 frags of 16x16x32.
// blockIdx.z selects a batch element (independent GEMM) from the arg struct.
struct GemmBatch {
    const unsigned short* a[8];
    const unsigned short* b[8];
    void* c[8];
};

template <int OUT_BF16, int TM>
__global__ __launch_bounds__(256, TM == 128 ? 2 : 4)
void gemm_kernel(GemmBatch args) {
    constexpr int NI = TM / 32;                       // m-frags per wave
    __shared__ __align__(16) unsigned short ldsA[TM * 64];   // panel p at p*TM*32
    __shared__ __align__(16) unsigned short ldsB[128 * 64];  // panel p at p*4096
    const unsigned short* __restrict__ A  = args.a[blockIdx.z];
    const unsigned short* __restrict__ Bt = args.b[blockIdx.z];
    void* __restrict__ Cout = args.c[blockIdx.z];

    const int t = threadIdx.x;
    const int n0 = blockIdx.x * 128;
    const int m0 = blockIdx.y * TM;
    const int lane = t & 63;
    const int wave = t >> 6;
    const int wm = (wave & 1) * (TM / 2);
    const int wn = (wave >> 1) * 64;
    const int fr = lane & 15;      // A: m in 16-tile; B: n in 16-tile; C: col
    const int quad = lane >> 4;    // k-group for frags; row-group for C

    f32x4 acc[NI][4] = {};

    const int sr = t >> 2;          // 0..63
    const int scol = (t & 3) * 8;   // 0,8,16,24
    const unsigned short* ga = A + (size_t)(m0 + sr) * QD + scol;
    const unsigned short* gb = Bt + (size_t)(n0 + sr) * QD + scol;
    unsigned short* la = ldsA + t * 8;
    unsigned short* lb = ldsB + t * 8;

    for (int k0 = 0; k0 < QD; k0 += 64) {
        __syncthreads();  // previous round's compute done before overwrite
        if constexpr (TM == 128) {
            async_load16(ga, la);
            async_load16(ga + 64 * QD, la + 2048);
            async_load16(ga + 32, la + 4096);
            async_load16(ga + 32 + 64 * QD, la + 6144);
        } else {
            async_load16(ga, la);
            async_load16(ga + 32, la + 2048);
        }
        async_load16(gb, lb);
        async_load16(gb + 64 * QD, lb + 2048);
        async_load16(gb + 32, lb + 4096);
        async_load16(gb + 32 + 64 * QD, lb + 6144);
        ga += 64;
        gb += 64;
        __syncthreads();  // staging complete

#pragma unroll
        for (int kk = 0; kk < 2; kk++) {
            const unsigned short* pa = ldsA + kk * (TM * 32);
            const unsigned short* pb = ldsB + kk * 4096;
            bf16x8 af[NI], bfr[4];
#pragma unroll
            for (int i = 0; i < NI; i++)
                af[i] = *(const bf16x8*)(pa + (wm + i * 16 + fr) * 32 + quad * 8);
#pragma unroll
            for (int j = 0; j < 4; j++)
                bfr[j] = *(const bf16x8*)(pb + (wn + j * 16 + fr) * 32 + quad * 8);
#pragma unroll
            for (int i = 0; i < NI; i++)
#pragma unroll
                for (int j = 0; j < 4; j++)
                    acc[i][j] = __builtin_amdgcn_mfma_f32_16x16x32_bf16(af[i], bfr[j],
                                                                        acc[i][j], 0, 0, 0);
        }
    }

    // epilogue: C/D layout col=lane&15, row=quad*4+reg  (m89/m91-verified)
#pragma unroll
    for (int i = 0; i < NI; i++) {
        const int gr = m0 + wm + i * 16 + quad * 4;
#pragma unroll
        for (int j = 0; j < 4; j++) {
            const int gc = n0 + wn + j * 16 + fr;
#pragma unroll
            for (int r = 0; r < 4; r++) {
                float v = acc[i][j][r];
                if (OUT_BF16)
                    ((unsigned short*)Cout)[(size_t)(gr + r) * QD + gc] = f2bf(v);
                else
                    ((float*)Cout)[(size_t)(gr + r) * QD + gc] = v;
            }
        }
    }
}

// ---------------------------------------------------------------------------
// Chain fold: out = x * (D1W1 * D2W2 * ... * D16W16 * M).
// Binary tree: 8 pair-products, 4, 2, 1, then *M, then one 4096-row apply.
// 275 GFLOP fold + 34 GFLOP apply vs 584 GFLOP for 17 sequential applies.
// Transposed tree nodes are produced directly via (AB)^T = B^T A^T by swapping
// operand roles (GEMM computes A * Bt^T; both operand forms are row-major
// [rows][k]); no transpose kernels needed anywhere.
extern "C" void kernel_launch(void* const* d_in, const int* in_sizes, int n_in,
                              void* d_out, int out_size, void* d_ws, size_t ws_size,
                              hipStream_t stream) {
    const float* input_state = (const float*)d_in[0];  // [4096][2048]
    const float* angles      = (const float*)d_in[1];  // [16][2048][3]
    const float* W           = (const float*)d_in[2];  // [16][2048][2048]
    const float* Mb          = (const float*)d_in[3];  // [2048][2048]

    const size_t mat = (size_t)QD * QD;                // elements per matrix
    char* ws = (char*)d_ws;
    float* scales = (float*)ws;                        // 128 KB
    size_t off = 131072;
    unsigned short* xb = (unsigned short*)(ws + off); off += (size_t)BATCH * QD * 2;  // 16 MB
    unsigned short* WA = (unsigned short*)(ws + off); off += 8 * mat * 2;   // 64 MB
    unsigned short* WB = (unsigned short*)(ws + off); off += 9 * mat * 2;   // 72 MB
    unsigned short* T1 = (unsigned short*)(ws + off); off += 8 * mat * 2;   // 64 MB
    unsigned short* T2 = (unsigned short*)(ws + off); off += 4 * mat * 2;   // 32 MB
    unsigned short* T3 = (unsigned short*)(ws + off); off += 2 * mat * 2;   // 16 MB
    unsigned short* T4 = (unsigned short*)(ws + off); off += mat * 2;       // 8 MB
    unsigned short* T5 = (unsigned short*)(ws + off); off += mat * 2;       // 8 MB
    // total ~280 MB; harness poison fills show ws >= 1 GiB.

    scales_kernel<<<(L_LAYERS * QD + 255) / 256, 256, 0, stream>>>(angles, scales,
                                                                   L_LAYERS * QD);
    convert_in_kernel<<<(BATCH * QD / 4) / 256, 256, 0, stream>>>(input_state, xb,
                                                                  BATCH * QD / 4);
    convert_a_all<<<dim3(mat / 4 / 256, 1, 8), 256, 0, stream>>>(W, scales, WA);
    convert_b_all<<<dim3(QD / 64, QD / 64, 9), 256, 0, stream>>>(W, Mb, scales, WB);

    // Level 1: pair i covers layers (2i, 2i+1). Even pairs -> normal product
    // P = A(W[2i]) * Bt(W[2i+1])^T; odd pairs -> transposed product
    // P^T = (W'[2i] W'[2i+1])^T = Bt(W[2i+1]) * A(W[2i])^T (operands swapped).
    GemmBatch b1{};
    for (int i = 0; i < 8; i++) {
        const unsigned short* wa = WA + (size_t)i * mat;
        const unsigned short* wb = WB + (size_t)i * mat;
        if ((i & 1) == 0) { b1.a[i] = wa; b1.b[i] = wb; }
        else              { b1.a[i] = wb; b1.b[i] = wa; }
        b1.c[i] = T1 + (size_t)i * mat;
    }
    gemm_kernel<1, 128><<<dim3(QD / 128, QD / 128, 8), 256, 0, stream>>>(b1);

    // Level 2: T1 holds [P1, P2^T, P3, P4^T, ...]. Even outputs normal
    // (Q = P_odd * (P_even^T)^T), odd outputs transposed (swap roles).
    GemmBatch b2{};
    for (int i = 0; i < 4; i++) {
        b2.a[i] = T1 + (size_t)(2 * i + (i & 1)) * mat;
        b2.b[i] = T1 + (size_t)(2 * i + 1 - (i & 1)) * mat;
        b2.c[i] = T2 + (size_t)i * mat;
    }
    gemm_kernel<1, 128><<<dim3(QD / 128, QD / 128, 4), 256, 0, stream>>>(b2);

    // Level 3
    GemmBatch b3{};
    for (int i = 0; i < 2; i++) {
        b3.a[i] = T2 + (size_t)(2 * i + (i & 1)) * mat;
        b3.b[i] = T2 + (size_t)(2 * i + 1 - (i & 1)) * mat;
        b3.c[i] = T3 + (size_t)i * mat;
    }
    gemm_kernel<1, 128><<<dim3(QD / 128, QD / 128, 2), 256, 0, stream>>>(b3);

    // Level 4: S = R1 * R2 = A(T3[0]) * Bt(T3[1])^T   (TM=64 -> 512 blocks)
    GemmBatch b4{};
    b4.a[0] = T3; b4.b[0] = T3 + mat; b4.c[0] = T4;
    gemm_kernel<1, 64><<<dim3(QD / 128, QD / 64, 1), 256, 0, stream>>>(b4);

    // Level 5: T^T = (S*M)^T = M^T * S^T = A(Mt) * Bt(S)^T
    GemmBatch b5{};
    b5.a[0] = WB + 8 * mat; b5.b[0] = T4; b5.c[0] = T5;
    gemm_kernel<1, 64><<<dim3(QD / 128, QD / 64, 1), 256, 0, stream>>>(b5);

    // Apply: out = x * T = A(xb) * Bt(T^T)^T, fp32 out
    GemmBatch ba{};
    ba.a[0] = xb; ba.b[0] = T5; ba.c[0] = d_out;
    gemm_kernel<0, 128><<<dim3(QD / 128, BATCH / 128, 1), 256, 0, stream>>>(ba);
}